// Round 1
// 127.872 us; speedup vs baseline: 1.0640x; 1.0640x over previous
//
#include <hip/hip_runtime.h>

// ---------------------------------------------------------------------------
// Fully-fused KAN-conv MLP: ONE BLOCK = ONE IMAGE, TWO WAVES per image.
// R14 vs R13: the grid (2048 one-wave blocks) capped occupancy at 8 waves/CU
// (2/SIMD) -> VALUBusy 54%, latency-bound. Split each image across 2 waves
// (128 threads, ~10 __syncthreads). 16 waves/CU (4/SIMD) + ~half the
// per-lane serial work. Aliased-LDS reuse (h1/h2/h3/fc1out inside bas) is
// kept safe by register-staging all reads before each barrier.
// Cardinal cubic B-spline: basis_j(x) = B3(u - j), u = 2.5x+5.5 (4 taps).
// ---------------------------------------------------------------------------

typedef _Float16 h2 __attribute__((ext_vector_type(2)));

__device__ __forceinline__ h2 u2h(unsigned int u) {
  union { unsigned int x; h2 h; } v; v.x = u; return v.h;
}
__device__ __forceinline__ unsigned short f2h_bits(float x) {
  union { _Float16 h; unsigned short u; } v; v.h = (_Float16)x; return v.u;
}
__device__ __forceinline__ float h2f(unsigned short u) {
  union { unsigned short u; _Float16 h; } v; v.u = u; return (float)v.h;
}
__device__ __forceinline__ unsigned int pack2h(float a, float b) {
  return (unsigned int)f2h_bits(a) | ((unsigned int)f2h_bits(b) << 16);
}
__device__ __forceinline__ float fdot2(h2 a, h2 b, float c) {
  return __builtin_amdgcn_fdot2(a, b, c, false);
}

// Basis window (8 f16 packed in uint4) + silu, all in registers.
__device__ __forceinline__ void featurize_regs(float v, uint4& bs, float& silu) {
  silu = v / (1.0f + __expf(-v));
  bs.x = 0u; bs.y = 0u; bs.z = 0u; bs.w = 0u;
  float u = fmaf(v, 2.5f, 5.5f);
  if (u >= 0.0f && u < 11.0f) {
    float tf = floorf(u);
    float f = u - tf, f2 = f * f, f3 = f2 * f, om = 1.0f - f;
    const float c6 = 1.0f / 6.0f;
    float w0 = om * om * om * c6;
    float w1 = (3.0f * f3 - 6.0f * f2 + 4.0f) * c6;
    float w2 = (-3.0f * f3 + 3.0f * f2 + 3.0f * f + 1.0f) * c6;
    float w3 = f3 * c6;
    unsigned long long w01 =
        (unsigned long long)f2h_bits(w0) |
        ((unsigned long long)f2h_bits(w1) << 16) |
        ((unsigned long long)f2h_bits(w2) << 32) |
        ((unsigned long long)f2h_bits(w3) << 48);
    int t = (int)tf;                 // 0..10; window starts at slot t-3
    int s = 16 * t - 48;             // bit shift into 128-bit field
    unsigned long long lo, hi;
    if (s >= 0) {
      lo = (s < 64) ? (w01 << s) : 0ull;
      hi = (s == 0) ? 0ull : ((s < 64) ? (w01 >> (64 - s)) : (w01 << (s - 64)));
    } else {
      lo = w01 >> (-s);
      hi = 0ull;
    }
    bs.x = (unsigned int)lo; bs.y = (unsigned int)(lo >> 32);
    bs.z = (unsigned int)hi; bs.w = (unsigned int)(hi >> 32);
  }
}

// ---------------- prep: conv weights + W1p4 + padded W2 ---------------------
__global__ __launch_bounds__(256) void k_prep(
    const float* __restrict__ bw1, const float* __restrict__ sw1,
    const float* __restrict__ bw2, const float* __restrict__ sw2,
    const float* __restrict__ bw3, const float* __restrict__ sw3,
    const float* __restrict__ w1, const float* __restrict__ w2,
    unsigned int* __restrict__ V1s, float* __restrict__ V1b,
    unsigned int* __restrict__ V2s, float* __restrict__ V2b,
    unsigned int* __restrict__ V3s, float* __restrict__ V3b,
    unsigned int* __restrict__ W1p4, float* __restrict__ W2p) {
  int t = blockIdx.x * 256 + threadIdx.x;
  if (t < 180) {  // L1: 9 taps x 5 outs x 4 pairs
    int p = t & 3, o = (t >> 2) % 5, in = t / 20;
    V1s[t] = pack2h(sw1[(o * 9 + in) * 8 + 2 * p], sw1[(o * 9 + in) * 8 + 2 * p + 1]);
  }
  if (t < 45)  { int o = t % 5, in = t / 5; V1b[t] = bw1[o * 9 + in]; }
  if (t < 900) { // L2: 45 taps x 5 outs x 4 pairs
    int p = t & 3, o = (t >> 2) % 5, in = t / 20;
    V2s[t] = pack2h(sw2[(o * 45 + in) * 8 + 2 * p], sw2[(o * 45 + in) * 8 + 2 * p + 1]);
  }
  if (t < 225) { int o = t % 5, in = t / 5; V2b[t] = bw2[o * 45 + in]; }
  if (t < 360) { // L3: 45 taps x 2 outs x 4 pairs
    int p = t & 3, o = (t >> 2) & 1, in = t / 8;
    V3s[t] = pack2h(sw3[(o * 45 + in) * 8 + 2 * p], sw3[(o * 45 + in) * 8 + 2 * p + 1]);
  }
  if (t < 90)  { int o = t % 2, in = t / 2; V3b[t] = bw3[o * 45 + in]; }
  if (t < 43008) {  // W1p4[((g*512)+o)*4+j]: j-th k-pair of group g, out o
    int j = t & 3, o = (t >> 2) & 511, g = t >> 11;
    int kp = g * 4 + j;
    W1p4[t] = (o < 500 && kp < 81)
                  ? pack2h(w1[o * 162 + 2 * kp], w1[o * 162 + 2 * kp + 1])
                  : 0u;
  }
  if (t < 5120) {   // W2p[10][512] zero-padded
    int o = t >> 9, k = t & 511;
    W2p[t] = (k < 500) ? w2[o * 500 + k] : 0.0f;
  }
}

// ---------------- the fused per-image kernel (two waves per block) ----------
__global__ __launch_bounds__(128, 4) void k_fused(
    const float* __restrict__ x,
    const unsigned int* __restrict__ V1s, const float* __restrict__ V1b,
    const unsigned int* __restrict__ V2s, const float* __restrict__ V2b,
    const unsigned int* __restrict__ V3s, const float* __restrict__ V3b,
    const unsigned int* __restrict__ W1p4, const float* __restrict__ W2p,
    const float* __restrict__ b1, const float* __restrict__ b2,
    float* __restrict__ out) {
  __shared__ uint4 bas[845];               // 13,520 B
  __shared__ unsigned short slu16[848];    //  1,696 B
  __shared__ float red[20];                // fc2 cross-wave scratch
  float*        basF = (float*)bas;        // dword view of bas
  float*        h3f  = basF + 2048;        // h3 (162 f), dead-by-order region
  unsigned int* hpk  = (unsigned int*)basF + 2560;  // 84 uints
  const int b = blockIdx.x;
  const int tid = threadIdx.x;             // 0..127, two waves

  // P1: featurize input image (784 px)
  #pragma unroll 1
  for (int l = tid; l < 784; l += 128) {
    uint4 bs; float sl;
    featurize_regs(x[b * 784 + l], bs, sl);
    bas[l] = bs; slu16[l] = f2h_bits(sl);
  }
  __syncthreads();

  // P2: conv1 (1->5) + 2x2 maxpool; 169 outputs in 2 chunks, staged in regs
  float h1v[2][5];
  #pragma unroll 1
  for (int it = 0; it < 2; ++it) {
    int p = it * 128 + tid;
    if (p < 169) {
      int py = p / 13, px = p % 13;
      int r0 = py * 2, c0 = px * 2;
      float wacc[4][5];
      #pragma unroll
      for (int wi = 0; wi < 4; ++wi)
        #pragma unroll
        for (int o = 0; o < 5; ++o) wacc[wi][o] = 0.0f;
      #pragma unroll
      for (int r = 0; r < 4; ++r) {
        uint4 q[4]; float sl[4];
        #pragma unroll
        for (int c = 0; c < 4; ++c) {
          q[c]  = bas[(r0 + r) * 28 + c0 + c];
          sl[c] = h2f(slu16[(r0 + r) * 28 + c0 + c]);
        }
        #pragma unroll
        for (int c = 0; c < 4; ++c) {
          h2 a0 = u2h(q[c].x), a1 = u2h(q[c].y), a2 = u2h(q[c].z), a3 = u2h(q[c].w);
          #pragma unroll
          for (int dy = 0; dy < 2; ++dy) {
            #pragma unroll
            for (int dx = 0; dx < 2; ++dx) {
              int ky = r - dy, kx = c - dx;
              if (ky >= 0 && ky < 3 && kx >= 0 && kx < 3) {
                const unsigned int* wp = V1s + (ky * 3 + kx) * 20;
                const float* bp = V1b + (ky * 3 + kx) * 5;
                #pragma unroll
                for (int o = 0; o < 5; ++o) {
                  float acc = wacc[dy * 2 + dx][o];
                  acc = fdot2(a0, u2h(wp[o * 4 + 0]), acc);
                  acc = fdot2(a1, u2h(wp[o * 4 + 1]), acc);
                  acc = fdot2(a2, u2h(wp[o * 4 + 2]), acc);
                  acc = fdot2(a3, u2h(wp[o * 4 + 3]), acc);
                  wacc[dy * 2 + dx][o] = fmaf(sl[c], bp[o], acc);
                }
              }
            }
          }
        }
      }
      #pragma unroll
      for (int o = 0; o < 5; ++o)
        h1v[it][o] = fmaxf(fmaxf(wacc[0][o], wacc[1][o]),
                           fmaxf(wacc[2][o], wacc[3][o]));
    }
  }
  __syncthreads();  // all conv1 LDS reads (both waves) done
  // write featurized h1 (aliases the input-pixel region)
  #pragma unroll 1
  for (int it = 0; it < 2; ++it) {
    int p = it * 128 + tid;
    if (p < 169) {
      #pragma unroll
      for (int o = 0; o < 5; ++o) {
        uint4 bs; float sl;
        featurize_regs(h1v[it][o], bs, sl);
        bas[o * 169 + p] = bs; slu16[o * 169 + p] = f2h_bits(sl);
      }
    }
  }
  __syncthreads();

  // P4: conv2 (5->5), one position per lane (121 < 128)
  float acc2[5];
  {
    #pragma unroll
    for (int o = 0; o < 5; ++o) acc2[o] = 0.0f;
    int pc = (tid < 121) ? tid : 120;     // clamp (writeback guarded)
    int y0 = pc / 11, x0 = pc % 11;
    #pragma unroll 1
    for (int cky = 0; cky < 15; ++cky) {
      int c = cky / 3, ky = cky - c * 3;
      int ba0 = c * 169 + (y0 + ky) * 13 + x0;
      uint4 q00 = bas[ba0], q01 = bas[ba0 + 1], q02 = bas[ba0 + 2];
      float s00 = h2f(slu16[ba0]), s01 = h2f(slu16[ba0 + 1]), s02 = h2f(slu16[ba0 + 2]);
      uint4 wq[15]; float wb[15];
      const uint4* wp4 = (const uint4*)(V2s + cky * 60);
      const float* bp  = V2b + cky * 15;
      #pragma unroll
      for (int i = 0; i < 15; ++i) { wq[i] = wp4[i]; wb[i] = bp[i]; }
      #pragma unroll
      for (int kx = 0; kx < 3; ++kx) {
        uint4 q = (kx == 0) ? q00 : ((kx == 1) ? q01 : q02);
        float sl = (kx == 0) ? s00 : ((kx == 1) ? s01 : s02);
        h2 a0 = u2h(q.x), a1 = u2h(q.y), a2 = u2h(q.z), a3 = u2h(q.w);
        #pragma unroll
        for (int o = 0; o < 5; ++o) {
          uint4 w = wq[kx * 5 + o];
          float a = acc2[o];
          a = fdot2(a0, u2h(w.x), a);
          a = fdot2(a1, u2h(w.y), a);
          a = fdot2(a2, u2h(w.z), a);
          a = fdot2(a3, u2h(w.w), a);
          acc2[o] = fmaf(sl, wb[kx * 5 + o], a);
        }
      }
    }
  }
  __syncthreads();  // all conv2 reads done before h2 overwrites bas
  if (tid < 121) {
    #pragma unroll
    for (int o = 0; o < 5; ++o) {
      uint4 bs; float sl;
      featurize_regs(acc2[o], bs, sl);
      bas[o * 121 + tid] = bs; slu16[o * 121 + tid] = f2h_bits(sl);
    }
  }
  __syncthreads();

  // P6: conv3 (5->2), one position per lane (81 < 128)
  float acc3[2];
  {
    acc3[0] = acc3[1] = 0.0f;
    int pc = (tid < 81) ? tid : 80;
    int y0 = pc / 9, x0 = pc % 9;
    #pragma unroll 1
    for (int cky = 0; cky < 15; ++cky) {
      int c = cky / 3, ky = cky - c * 3;
      int ba0 = c * 121 + (y0 + ky) * 11 + x0;
      uint4 q00 = bas[ba0], q01 = bas[ba0 + 1], q02 = bas[ba0 + 2];
      float s00 = h2f(slu16[ba0]), s01 = h2f(slu16[ba0 + 1]), s02 = h2f(slu16[ba0 + 2]);
      uint4 wq[6]; float wb[6];
      const uint4* wp4 = (const uint4*)(V3s + cky * 24);
      const float* bp  = V3b + cky * 6;
      #pragma unroll
      for (int i = 0; i < 6; ++i) { wq[i] = wp4[i]; wb[i] = bp[i]; }
      #pragma unroll
      for (int kx = 0; kx < 3; ++kx) {
        uint4 q = (kx == 0) ? q00 : ((kx == 1) ? q01 : q02);
        float sl = (kx == 0) ? s00 : ((kx == 1) ? s01 : s02);
        h2 a0 = u2h(q.x), a1 = u2h(q.y), a2 = u2h(q.z), a3 = u2h(q.w);
        #pragma unroll
        for (int o = 0; o < 2; ++o) {
          uint4 w = wq[kx * 2 + o];
          float a = acc3[o];
          a = fdot2(a0, u2h(w.x), a);
          a = fdot2(a1, u2h(w.y), a);
          a = fdot2(a2, u2h(w.z), a);
          a = fdot2(a3, u2h(w.w), a);
          acc3[o] = fmaf(sl, wb[kx * 2 + o], a);
        }
      }
    }
  }
  __syncthreads();  // all conv3 reads done before h3 overwrites bas region
  if (tid < 81) { h3f[tid] = acc3[0]; h3f[81 + tid] = acc3[1]; }
  __syncthreads();
  if (tid < 84)
    hpk[tid] = (tid < 81) ? pack2h(h3f[2 * tid], h3f[2 * tid + 1]) : 0u;
  __syncthreads();

  // P7: fc1 (162->500) + bias + ReLU; 4 outs/lane; double-buffered global
  // loads (vmcnt is in-order & separate from LDS lgkmcnt -> real prefetch).
  float fa[4];
  #pragma unroll
  for (int i = 0; i < 4; ++i) fa[i] = 0.0f;
  {
    const uint4* hp4 = (const uint4*)hpk;
    const uint4* wbase = (const uint4*)W1p4 + tid;
    uint4 wA[4], wB[4];
    #pragma unroll
    for (int i = 0; i < 4; ++i) wA[i] = wbase[i * 128];   // group 0
    #pragma unroll 1
    for (int g = 0; g < 21; g += 2) {
      if (g + 1 < 21) {
        const uint4* p = wbase + (g + 1) * 512;
        #pragma unroll
        for (int i = 0; i < 4; ++i) wB[i] = p[i * 128];
      }
      {
        uint4 hk = hp4[g];
        #pragma unroll
        for (int i = 0; i < 4; ++i) {
          float a = fa[i];
          a = fdot2(u2h(hk.x), u2h(wA[i].x), a);
          a = fdot2(u2h(hk.y), u2h(wA[i].y), a);
          a = fdot2(u2h(hk.z), u2h(wA[i].z), a);
          a = fdot2(u2h(hk.w), u2h(wA[i].w), a);
          fa[i] = a;
        }
      }
      if (g + 2 < 21) {
        const uint4* p = wbase + (g + 2) * 512;
        #pragma unroll
        for (int i = 0; i < 4; ++i) wA[i] = p[i * 128];
      }
      if (g + 1 < 21) {
        uint4 hk = hp4[g + 1];
        #pragma unroll
        for (int i = 0; i < 4; ++i) {
          float a = fa[i];
          a = fdot2(u2h(hk.x), u2h(wB[i].x), a);
          a = fdot2(u2h(hk.y), u2h(wB[i].y), a);
          a = fdot2(u2h(hk.z), u2h(wB[i].z), a);
          a = fdot2(u2h(hk.w), u2h(wB[i].w), a);
          fa[i] = a;
        }
      }
    }
  }
  #pragma unroll
  for (int i = 0; i < 4; ++i) {
    int o = tid + 128 * i;
    float bb = (o < 500) ? b1[o] : 0.0f;
    float v = fa[i] + bb;
    basF[o] = (v > 0.0f && o < 500) ? v : 0.0f;  // fc1out[512] in bas[0..127]
  }
  __syncthreads();

  // P8: fc2 (500->10): lane covers k = 4*tid..4*tid+3, shfl + LDS reduction
  float acc10[10];
  {
    float4 ha = ((const float4*)basF)[tid];
    #pragma unroll
    for (int o = 0; o < 10; ++o) {
      const float4* wp = (const float4*)&W2p[o * 512 + 4 * tid];
      float4 w = wp[0];
      acc10[o] = ha.x * w.x + ha.y * w.y + ha.z * w.z + ha.w * w.w;
    }
  }
  #pragma unroll
  for (int off = 32; off > 0; off >>= 1) {
    #pragma unroll
    for (int o = 0; o < 10; ++o) acc10[o] += __shfl_down(acc10[o], off);
  }
  if ((tid & 63) == 0) {
    int wid = tid >> 6;
    #pragma unroll
    for (int o = 0; o < 10; ++o) red[wid * 10 + o] = acc10[o];
  }
  __syncthreads();
  if (tid < 10) out[b * 10 + tid] = red[tid] + red[10 + tid] + b2[tid];
}

// ---------------------------------------------------------------------------
extern "C" void kernel_launch(void* const* d_in, const int* in_sizes, int n_in,
                              void* d_out, int out_size, void* d_ws, size_t ws_size,
                              hipStream_t stream) {
  (void)in_sizes; (void)n_in; (void)out_size; (void)ws_size;
  const float* x   = (const float*)d_in[0];
  const float* bw1 = (const float*)d_in[1];
  const float* sw1 = (const float*)d_in[2];
  const float* bw2 = (const float*)d_in[3];
  const float* sw2 = (const float*)d_in[4];
  const float* bw3 = (const float*)d_in[5];
  const float* sw3 = (const float*)d_in[6];
  const float* w1  = (const float*)d_in[7];
  const float* b1  = (const float*)d_in[8];
  const float* w2  = (const float*)d_in[9];
  const float* b2  = (const float*)d_in[10];
  float* out = (float*)d_out;

  char* ws = (char*)d_ws;
  unsigned int* V1s  = (unsigned int*)(ws);           // 180 u   (720 B)
  float*        V1b  = (float*)(ws + 768);            // 45 f    (180 B)
  unsigned int* V2s  = (unsigned int*)(ws + 1024);    // 900 u   (3,600 B)
  float*        V2b  = (float*)(ws + 4672);           // 225 f   (900 B)
  unsigned int* V3s  = (unsigned int*)(ws + 5632);    // 360 u   (1,440 B)
  float*        V3b  = (float*)(ws + 7168);           // 90 f    (360 B)
  float*        W2p  = (float*)(ws + 7680);           // 5,120 f (20,480 B)
  unsigned int* W1p4 = (unsigned int*)(ws + 28672);   // 43,008 u (172,032 B)

  k_prep<<<168, 256, 0, stream>>>(bw1, sw1, bw2, sw2, bw3, sw3, w1, w2,
                                  V1s, V1b, V2s, V2b, V3s, V3b, W1p4, W2p);
  k_fused<<<2048, 128, 0, stream>>>(x, V1s, V1b, V2s, V2b, V3s, V3b,
                                    W1p4, W2p, b1, b2, out);
}